// Round 2
// baseline (9172.572 us; speedup 1.0000x reference)
//
#include <hip/hip_runtime.h>
#include <math.h>

#define SS 4
#define BB 4
#define CC 64
#define HH 32
#define WW 32
#define HWD 1024          // H*W
#define CHW (CC*HWD)      // 65536
#define NIMG (SS*BB)      // 16

// ---------------------------------------------------------------------------
// Kernel 1: triple 3x3 conv (ft, ht, lt) from h
// grid (16 img, 64 co), block 256
// ---------------------------------------------------------------------------
__global__ __launch_bounds__(256) void conv3_triple_kernel(
    const float* __restrict__ h,
    const float* __restrict__ wf, const float* __restrict__ bf,
    const float* __restrict__ wh, const float* __restrict__ bh,
    const float* __restrict__ wl, const float* __restrict__ bl,
    float* __restrict__ ft, float* __restrict__ ht, float* __restrict__ lt)
{
    int img = blockIdx.x;
    int co  = blockIdx.y;
    __shared__ float tile[34*34];
    int tid = threadIdx.x;
    float accf[4] = {0,0,0,0}, acch[4] = {0,0,0,0}, accl[4] = {0,0,0,0};
    int px0 = tid * 4;
    int oy = px0 >> 5;
    int ox = px0 & 31;
    const float* hin = h + (size_t)img * CHW;
    for (int ci = 0; ci < CC; ++ci) {
        __syncthreads();
        for (int idx = tid; idx < 34*34; idx += 256) {
            int r = idx / 34 - 1, c = idx % 34 - 1;
            float v = 0.f;
            if ((unsigned)r < 32u && (unsigned)c < 32u) v = hin[ci*HWD + r*WW + c];
            tile[idx] = v;
        }
        __syncthreads();
        const float* pwf = wf + (co*CC + ci)*9;
        const float* pwh = wh + (co*CC + ci)*9;
        const float* pwl = wl + (co*CC + ci)*9;
        float wfv[9], whv[9], wlv[9];
        #pragma unroll
        for (int k = 0; k < 9; ++k) { wfv[k]=pwf[k]; whv[k]=pwh[k]; wlv[k]=pwl[k]; }
        #pragma unroll
        for (int dy = 0; dy < 3; ++dy) {
            const float* trow = &tile[(oy+dy)*34 + ox];
            float in[6];
            #pragma unroll
            for (int q = 0; q < 6; ++q) in[q] = trow[q];
            #pragma unroll
            for (int dx = 0; dx < 3; ++dx) {
                float a = wfv[dy*3+dx], b = whv[dy*3+dx], c = wlv[dy*3+dx];
                #pragma unroll
                for (int p = 0; p < 4; ++p) {
                    accf[p] += a * in[dx+p];
                    acch[p] += b * in[dx+p];
                    accl[p] += c * in[dx+p];
                }
            }
        }
    }
    float bfv = bf[co], bhv = bh[co], blv = bl[co];
    size_t out = (size_t)img*CHW + co*HWD + px0;
    #pragma unroll
    for (int p = 0; p < 4; ++p) {
        ft[out+p] = accf[p] + bfv;
        ht[out+p] = acch[p] + bhv;
        lt[out+p] = accl[p] + blv;
    }
}

// ---------------------------------------------------------------------------
// Flash attention core: Q,K,V,O are [64][1024] (channel-major).
// O[c,m] = sum_n softmax_n(Q[:,m].K[:,n]) * V[c,n]
// block: 256 threads; thread t -> m = m0 + (t>>2), channel quarter cq = t&3
// ---------------------------------------------------------------------------
__device__ __forceinline__ void flash_core(
    const float* __restrict__ Q, const float* __restrict__ K,
    const float* __restrict__ V, float* __restrict__ O, int m0)
{
    __shared__ float kt[64*65];
    __shared__ float vt[64*65];
    int tid = threadIdx.x;
    int ml = tid >> 2;
    int cq = tid & 3;
    int m = m0 + ml;
    float q[16];
    #pragma unroll
    for (int k = 0; k < 16; ++k) q[k] = Q[(cq*16+k)*HWD + m];
    float acc[16];
    #pragma unroll
    for (int k = 0; k < 16; ++k) acc[k] = 0.f;
    float mx = -3.0e38f, l = 0.f;

    for (int nt = 0; nt < 16; ++nt) {
        int n0 = nt * 64;
        __syncthreads();
        for (int idx = tid; idx < 64*64; idx += 256) {
            int r = idx >> 6, c = idx & 63;
            kt[r*65+c] = K[r*HWD + n0 + c];
            vt[r*65+c] = V[r*HWD + n0 + c];
        }
        __syncthreads();
        float s[64];
        #pragma unroll
        for (int n = 0; n < 64; ++n) {
            float a = 0.f;
            #pragma unroll
            for (int k = 0; k < 16; ++k) a += q[k] * kt[(cq*16+k)*65 + n];
            s[n] = a;
        }
        #pragma unroll
        for (int n = 0; n < 64; ++n) {
            s[n] += __shfl_xor(s[n], 1);
            s[n] += __shfl_xor(s[n], 2);
        }
        float tm = s[0];
        #pragma unroll
        for (int n = 1; n < 64; ++n) tm = fmaxf(tm, s[n]);
        float nmx = fmaxf(mx, tm);
        float sc = __expf(mx - nmx);
        float ts = 0.f;
        #pragma unroll
        for (int n = 0; n < 64; ++n) { s[n] = __expf(s[n] - nmx); ts += s[n]; }
        l = l * sc + ts;
        mx = nmx;
        #pragma unroll
        for (int k = 0; k < 16; ++k) {
            float a = acc[k] * sc;
            #pragma unroll
            for (int n = 0; n < 64; ++n) a += s[n] * vt[(cq*16+k)*65 + n];
            acc[k] = a;
        }
    }
    float inv = 1.f / l;
    #pragma unroll
    for (int k = 0; k < 16; ++k) O[(cq*16+k)*HWD + m] = acc[k] * inv;
}

// grid (16 m-tiles, 16 inst)
__global__ __launch_bounds__(256) void flash_intra_kernel(
    const float* __restrict__ ft, const float* __restrict__ ht,
    const float* __restrict__ lt, float* __restrict__ ctx)
{
    int inst = blockIdx.y;
    int m0 = blockIdx.x * 64;
    flash_core(ft + (size_t)inst*CHW, ht + (size_t)inst*CHW,
               lt + (size_t)inst*CHW, ctx + (size_t)inst*CHW, m0);
}

// grid (16 m-tiles, 16 inst = i*B+b); j fixed per launch
__global__ __launch_bounds__(256) void flash_inter_kernel(
    const float* __restrict__ h, const float* __restrict__ yt,
    float* __restrict__ mji, int j)
{
    int inst = blockIdx.y;     // i*4 + b
    int b = inst & 3;
    int m0 = blockIdx.x * 64;
    flash_core(h + (size_t)inst*CHW, yt + (size_t)(j*BB+b)*CHW,
               h + (size_t)(j*BB+b)*CHW, mji + (size_t)inst*CHW, m0);
}

// ---------------------------------------------------------------------------
// yt[img,c,n] = sum_d Wc[c,d] * h[img,d,n]    grid (16, 8 n-chunks of 128)
// ---------------------------------------------------------------------------
__global__ __launch_bounds__(256) void yt_kernel(
    const float* __restrict__ Wc, const float* __restrict__ h,
    float* __restrict__ yt)
{
    int img = blockIdx.x;
    int n0 = blockIdx.y * 128;
    __shared__ float wc[64*64];
    __shared__ float hs[64*128];
    int tid = threadIdx.x;
    for (int i = tid; i < 4096; i += 256) wc[i] = Wc[i];
    for (int i = tid; i < 64*128; i += 256) {
        int d = i >> 7, n = i & 127;
        hs[i] = h[(size_t)img*CHW + d*HWD + n0 + n];
    }
    __syncthreads();
    int n = tid & 127;
    int c0 = (tid >> 7) * 32;
    for (int c = c0; c < c0+32; ++c) {
        float a = 0.f;
        #pragma unroll 8
        for (int d = 0; d < 64; ++d) a += wc[c*64+d] * hs[d*128+n];
        yt[(size_t)img*CHW + c*HWD + n0 + n] = a;
    }
}

// ---------------------------------------------------------------------------
// Gate: closed-form mean of padded 3x3 conv.
// stats per (img,ci): F, top, bottom, left, right, TL, TR, BL, BR
// grid 1024 (img*64+ci), block 64 (one wave)
// ---------------------------------------------------------------------------
__global__ __launch_bounds__(64) void gate_stats_kernel(
    const float* __restrict__ mji, float* __restrict__ stats)
{
    int img = blockIdx.x >> 6;
    int ci  = blockIdx.x & 63;
    const float* p = mji + ((size_t)img*CC + ci)*HWD;
    int l = threadIdx.x;
    float full=0, top=0, bot=0, left=0, right=0;
    #pragma unroll
    for (int k = 0; k < 16; ++k) {
        int px = l + 64*k;
        float v = p[px];
        int y = px >> 5, x = px & 31;
        full += v;
        if (y == 0)  top += v;
        if (y == 31) bot += v;
        if (x == 0)  left += v;
        if (x == 31) right += v;
    }
    #pragma unroll
    for (int msk = 1; msk < 64; msk <<= 1) {
        full  += __shfl_xor(full,  msk);
        top   += __shfl_xor(top,   msk);
        bot   += __shfl_xor(bot,   msk);
        left  += __shfl_xor(left,  msk);
        right += __shfl_xor(right, msk);
    }
    if (l == 0) {
        float* o = stats + ((size_t)img*CC + ci)*9;
        o[0]=full; o[1]=top; o[2]=bot; o[3]=left; o[4]=right;
        o[5]=p[0]; o[6]=p[31]; o[7]=p[992]; o[8]=p[1023];
    }
}

// gji[img,o] = sigmoid( (1/1024)*sum_spatial conv + bias )   grid 16, block 64
__global__ __launch_bounds__(64) void gate_gji_kernel(
    const float* __restrict__ stats, const float* __restrict__ wg,
    const float* __restrict__ bg, float* __restrict__ gji)
{
    int img = blockIdx.x;
    int o = threadIdx.x;
    float acc = 0.f;
    for (int ci = 0; ci < CC; ++ci) {
        const float* st = stats + ((size_t)img*CC + ci)*9;
        float F=st[0], T=st[1], Bo=st[2], L=st[3], R=st[4];
        float TL=st[5], TR=st[6], BL=st[7], BR=st[8];
        const float* w = wg + (o*CC + ci)*9;
        float S00 = F - Bo - R + BR;
        float S01 = F - Bo;
        float S02 = F - Bo - L + BL;
        float S10 = F - R;
        float S11 = F;
        float S12 = F - L;
        float S20 = F - T - R + TR;
        float S21 = F - T;
        float S22 = F - T - L + TL;
        acc += w[0]*S00 + w[1]*S01 + w[2]*S02
             + w[3]*S10 + w[4]*S11 + w[5]*S12
             + w[6]*S20 + w[7]*S21 + w[8]*S22;
    }
    float m = acc * (1.f/1024.f) + bg[o];
    gji[img*CC + o] = 1.f / (1.f + __expf(-m));
}

// inter_acc[i,b,c,m] (+)= (j!=i) * gji[i*4+b, c] * mji[i*4+b, c, m]
__global__ __launch_bounds__(256) void inter_accum_kernel(
    const float* __restrict__ mji, const float* __restrict__ gji,
    float* __restrict__ acc, int j, int init)
{
    int idx = blockIdx.x * 256 + threadIdx.x;
    int iimg = idx >> 16;
    int c = (idx >> 10) & 63;
    int i = iimg >> 2;
    float v = (j != i) ? gji[iimg*CC + c] * mji[idx] : 0.f;
    if (init) acc[idx] = v; else acc[idx] += v;
}

// agg = intra_w*(alpha*ctx + h) + inter_w*(scale_c*inter_acc + 3*(beta - mean*scale))
__global__ __launch_bounds__(256) void agg_kernel(
    const float* __restrict__ ctx, const float* __restrict__ h,
    const float* __restrict__ acc, const float* __restrict__ alpha,
    const float* __restrict__ bn_gamma, const float* __restrict__ bn_beta,
    const float* __restrict__ bn_mean, const float* __restrict__ bn_var,
    const float* __restrict__ intra_w, const float* __restrict__ inter_w,
    float* __restrict__ agg)
{
    int idx = blockIdx.x * 256 + threadIdx.x;
    int c = (idx >> 10) & 63;
    float scale = bn_gamma[c] / sqrtf(bn_var[c] + 1e-5f);
    float cst = 3.f * (bn_beta[c] - bn_mean[c]*scale);
    float intra = alpha[0]*ctx[idx] + h[idx];
    float inter = scale*acc[idx] + cst;
    agg[idx] = intra_w[0]*intra + inter_w[0]*inter;
}

// ---------------------------------------------------------------------------
// 5x5 conv, 128 in-ch (agg | h), 128 out-ch, sigmoid -> zr. grid (16,128)
// ---------------------------------------------------------------------------
__global__ __launch_bounds__(256) void conv5_zr_kernel(
    const float* __restrict__ agg, const float* __restrict__ h,
    const float* __restrict__ w, const float* __restrict__ bias,
    float* __restrict__ zr)
{
    int img = blockIdx.x;
    int co  = blockIdx.y;
    __shared__ float tile[36*36];
    int tid = threadIdx.x;
    float acc[4] = {0,0,0,0};
    int px0 = tid * 4;
    int oy = px0 >> 5, ox = px0 & 31;
    for (int ci = 0; ci < 128; ++ci) {
        const float* src = (ci < 64) ? (agg + (size_t)img*CHW + ci*HWD)
                                     : (h + (size_t)img*CHW + (ci-64)*HWD);
        __syncthreads();
        for (int idx = tid; idx < 36*36; idx += 256) {
            int r = idx / 36 - 2, c = idx % 36 - 2;
            float v = 0.f;
            if ((unsigned)r < 32u && (unsigned)c < 32u) v = src[r*WW + c];
            tile[idx] = v;
        }
        __syncthreads();
        const float* pw = w + (co*128 + ci)*25;
        float wv[25];
        #pragma unroll
        for (int k = 0; k < 25; ++k) wv[k] = pw[k];
        #pragma unroll
        for (int dy = 0; dy < 5; ++dy) {
            const float* trow = &tile[(oy+dy)*36 + ox];
            float in[8];
            #pragma unroll
            for (int q = 0; q < 8; ++q) in[q] = trow[q];
            #pragma unroll
            for (int dx = 0; dx < 5; ++dx) {
                float wk = wv[dy*5+dx];
                #pragma unroll
                for (int p = 0; p < 4; ++p) acc[p] += wk * in[dx+p];
            }
        }
    }
    float bv = bias[co];
    size_t out = (size_t)img*128*HWD + co*HWD + px0;
    #pragma unroll
    for (int p = 0; p < 4; ++p)
        zr[out+p] = 1.f / (1.f + __expf(-(acc[p] + bv)));
}

// 5x5 conv, 128 in-ch (agg | r*h), 64 out-ch, tanh -> h_hat. grid (16,64)
__global__ __launch_bounds__(256) void conv5_hh_kernel(
    const float* __restrict__ agg, const float* __restrict__ h,
    const float* __restrict__ zr, const float* __restrict__ w,
    const float* __restrict__ bias, float* __restrict__ hh)
{
    int img = blockIdx.x;
    int co  = blockIdx.y;
    __shared__ float tile[36*36];
    int tid = threadIdx.x;
    float acc[4] = {0,0,0,0};
    int px0 = tid * 4;
    int oy = px0 >> 5, ox = px0 & 31;
    for (int ci = 0; ci < 128; ++ci) {
        __syncthreads();
        if (ci < 64) {
            const float* src = agg + (size_t)img*CHW + ci*HWD;
            for (int idx = tid; idx < 36*36; idx += 256) {
                int r = idx / 36 - 2, c = idx % 36 - 2;
                float v = 0.f;
                if ((unsigned)r < 32u && (unsigned)c < 32u) v = src[r*WW + c];
                tile[idx] = v;
            }
        } else {
            const float* srcH = h + (size_t)img*CHW + (ci-64)*HWD;
            const float* srcR = zr + (size_t)img*128*HWD + ci*HWD;  // r channel = 64+(ci-64)=ci
            for (int idx = tid; idx < 36*36; idx += 256) {
                int r = idx / 36 - 2, c = idx % 36 - 2;
                float v = 0.f;
                if ((unsigned)r < 32u && (unsigned)c < 32u) v = srcH[r*WW + c] * srcR[r*WW + c];
                tile[idx] = v;
            }
        }
        __syncthreads();
        const float* pw = w + (co*128 + ci)*25;
        float wv[25];
        #pragma unroll
        for (int k = 0; k < 25; ++k) wv[k] = pw[k];
        #pragma unroll
        for (int dy = 0; dy < 5; ++dy) {
            const float* trow = &tile[(oy+dy)*36 + ox];
            float in[8];
            #pragma unroll
            for (int q = 0; q < 8; ++q) in[q] = trow[q];
            #pragma unroll
            for (int dx = 0; dx < 5; ++dx) {
                float wk = wv[dy*5+dx];
                #pragma unroll
                for (int p = 0; p < 4; ++p) acc[p] += wk * in[dx+p];
            }
        }
    }
    float bv = bias[co];
    size_t out = (size_t)img*CHW + co*HWD + px0;
    #pragma unroll
    for (int p = 0; p < 4; ++p) hh[out+p] = tanhf(acc[p] + bv);
}

// h = (2-z)*h + z*h_hat
__global__ __launch_bounds__(256) void gru_update_kernel(
    const float* __restrict__ zr, const float* __restrict__ hh,
    float* __restrict__ h)
{
    int idx = blockIdx.x * 256 + threadIdx.x;
    int img = idx >> 16;
    int rem = idx & 65535;
    float z = zr[(size_t)img*131072 + rem];   // channels 0..63
    float hv = h[idx], hhv = hh[idx];
    h[idx] = (2.f - z) * hv + z * hhv;
}

// ---------------------------------------------------------------------------
extern "C" void kernel_launch(void* const* d_in, const int* in_sizes, int n_in,
                              void* d_out, int out_size, void* d_ws, size_t ws_size,
                              hipStream_t stream)
{
    const float* x        = (const float*)d_in[0];
    const float* Wf_w     = (const float*)d_in[1];
    const float* Wf_b     = (const float*)d_in[2];
    const float* Wh_w     = (const float*)d_in[3];
    const float* Wh_b     = (const float*)d_in[4];
    const float* Wl_w     = (const float*)d_in[5];
    const float* Wl_b     = (const float*)d_in[6];
    const float* alpha    = (const float*)d_in[7];
    const float* Wc       = (const float*)d_in[8];
    const float* Wg_w     = (const float*)d_in[9];
    const float* Wg_b     = (const float*)d_in[10];
    const float* bn_gamma = (const float*)d_in[11];
    const float* bn_beta  = (const float*)d_in[12];
    const float* bn_mean  = (const float*)d_in[13];
    const float* bn_var   = (const float*)d_in[14];
    const float* gru_zr_w = (const float*)d_in[15];
    const float* gru_zr_b = (const float*)d_in[16];
    const float* gru_h_w  = (const float*)d_in[17];
    const float* gru_h_b  = (const float*)d_in[18];
    const float* intra_w  = (const float*)d_in[19];
    const float* inter_w  = (const float*)d_in[20];

    float* h  = (float*)d_out;                  // 16*64*1024 = 1M floats
    float* ws = (float*)d_ws;
    const size_t M = 1048576;
    float* ft    = ws;            // later reused as agg
    float* ht_   = ws + 1*M;      // later reused as zr (2M, spans ht_+lt)
    float* lt    = ws + 2*M;
    float* ctx   = ws + 3*M;
    float* yt    = ws + 4*M;      // later reused as h_hat
    float* mji   = ws + 5*M;
    float* iacc  = ws + 6*M;
    float* stats = ws + 7*M;
    float* gji   = stats + 16384;
    float* agg   = ft;
    float* zr    = ht_;
    float* hh    = yt;

    hipMemcpyAsync(h, x, M * sizeof(float), hipMemcpyDeviceToDevice, stream);

    for (int it = 0; it < 3; ++it) {
        conv3_triple_kernel<<<dim3(NIMG, CC), 256, 0, stream>>>(
            h, Wf_w, Wf_b, Wh_w, Wh_b, Wl_w, Wl_b, ft, ht_, lt);
        flash_intra_kernel<<<dim3(16, NIMG), 256, 0, stream>>>(ft, ht_, lt, ctx);
        yt_kernel<<<dim3(NIMG, 8), 256, 0, stream>>>(Wc, h, yt);
        for (int j = 0; j < SS; ++j) {
            flash_inter_kernel<<<dim3(16, NIMG), 256, 0, stream>>>(h, yt, mji, j);
            gate_stats_kernel<<<1024, 64, 0, stream>>>(mji, stats);
            gate_gji_kernel<<<16, 64, 0, stream>>>(stats, Wg_w, Wg_b, gji);
            inter_accum_kernel<<<4096, 256, 0, stream>>>(mji, gji, iacc, j, j == 0 ? 1 : 0);
        }
        agg_kernel<<<4096, 256, 0, stream>>>(ctx, h, iacc, alpha,
            bn_gamma, bn_beta, bn_mean, bn_var, intra_w, inter_w, agg);
        conv5_zr_kernel<<<dim3(NIMG, 128), 256, 0, stream>>>(agg, h, gru_zr_w, gru_zr_b, zr);
        conv5_hh_kernel<<<dim3(NIMG, 64), 256, 0, stream>>>(agg, h, zr, gru_h_w, gru_h_b, hh);
        gru_update_kernel<<<4096, 256, 0, stream>>>(zr, hh, h);
    }
}

// Round 11
// 7395.339 us; speedup vs baseline: 1.2403x; 1.2403x over previous
//
#include <hip/hip_runtime.h>
#include <math.h>

#define SS 4
#define BB 4
#define CC 64
#define HWD 1024          // H*W
#define CHW (CC*HWD)      // 65536
#define NIMG (SS*BB)      // 16

// ---------------------------------------------------------------------------
// Triple 3x3 conv (ft, ht, lt) from h. grid (16 img, 64 co), block 256.
// Tile: 34 rows x 36 cols, halo (=zero-pad) initialized once; per-ci only the
// 32x32 interior is restaged. Read base (oy+dy)*36+ox is 16B-aligned.
// ---------------------------------------------------------------------------
__global__ __launch_bounds__(256) void conv3_triple_kernel(
    const float* __restrict__ h,
    const float* __restrict__ wf, const float* __restrict__ bf,
    const float* __restrict__ wh, const float* __restrict__ bh,
    const float* __restrict__ wl, const float* __restrict__ bl,
    float* __restrict__ ft, float* __restrict__ ht, float* __restrict__ lt)
{
    int img = blockIdx.x;
    int co  = blockIdx.y;
    __shared__ __align__(16) float tile[34*36];
    int tid = threadIdx.x;
    float accf[4] = {0,0,0,0}, acch[4] = {0,0,0,0}, accl[4] = {0,0,0,0};
    int px0 = tid * 4;
    int oy = px0 >> 5;
    int ox = px0 & 31;
    const float* hin = h + (size_t)img * CHW;
    for (int idx = tid; idx < 34*36; idx += 256) tile[idx] = 0.f;
    int sr = tid >> 3;            // 0..31
    int sc = (tid & 7) * 4;       // 0..28
    for (int ci = 0; ci < CC; ++ci) {
        __syncthreads();
        {
            float4 v = *(const float4*)(hin + ci*HWD + sr*32 + sc);
            float* dst = &tile[(sr+1)*36 + 1 + sc];
            dst[0]=v.x; dst[1]=v.y; dst[2]=v.z; dst[3]=v.w;
        }
        __syncthreads();
        const float* pwf = wf + (co*CC + ci)*9;
        const float* pwh = wh + (co*CC + ci)*9;
        const float* pwl = wl + (co*CC + ci)*9;
        float wfv[9], whv[9], wlv[9];
        #pragma unroll
        for (int k = 0; k < 9; ++k) { wfv[k]=pwf[k]; whv[k]=pwh[k]; wlv[k]=pwl[k]; }
        #pragma unroll
        for (int dy = 0; dy < 3; ++dy) {
            const float* trow = &tile[(oy+dy)*36 + ox];
            float4 a4 = *(const float4*)trow;
            float2 b2 = *(const float2*)(trow + 4);
            float in[6] = {a4.x, a4.y, a4.z, a4.w, b2.x, b2.y};
            #pragma unroll
            for (int dx = 0; dx < 3; ++dx) {
                float a = wfv[dy*3+dx], b = whv[dy*3+dx], c = wlv[dy*3+dx];
                #pragma unroll
                for (int p = 0; p < 4; ++p) {
                    accf[p] += a * in[dx+p];
                    acch[p] += b * in[dx+p];
                    accl[p] += c * in[dx+p];
                }
            }
        }
    }
    float bfv = bf[co], bhv = bh[co], blv = bl[co];
    size_t out = (size_t)img*CHW + co*HWD + px0;
    float4 rf = {accf[0]+bfv, accf[1]+bfv, accf[2]+bfv, accf[3]+bfv};
    float4 rh = {acch[0]+bhv, acch[1]+bhv, acch[2]+bhv, acch[3]+bhv};
    float4 rl = {accl[0]+blv, accl[1]+blv, accl[2]+blv, accl[3]+blv};
    *(float4*)(ft + out) = rf;
    *(float4*)(ht + out) = rh;
    *(float4*)(lt + out) = rl;
}

// ---------------------------------------------------------------------------
// Flash attention core, float4 LDS with XOR swizzle (phys col = log col ^ cq
// per 16-row group) -> conflict-free ds_read_b128.
// thread t -> m = m0 + (t>>2), channel quarter cq = t&3 (16 ch each).
// ---------------------------------------------------------------------------
__device__ __forceinline__ void flash_core(
    const float* __restrict__ Q, const float* __restrict__ K,
    const float* __restrict__ V, float* __restrict__ O, int m0,
    float4* kt4, float4* vt4)
{
    int tid = threadIdx.x;
    int cq = tid & 3;
    int m = m0 + (tid >> 2);
    float q[16];
    #pragma unroll
    for (int k = 0; k < 16; ++k) q[k] = Q[(cq*16+k)*HWD + m];
    float acc[16];
    #pragma unroll
    for (int k = 0; k < 16; ++k) acc[k] = 0.f;
    float mx = -3.0e38f, l = 0.f;

    for (int nt = 0; nt < 16; ++nt) {
        int n0 = nt * 64;
        __syncthreads();
        #pragma unroll
        for (int t = 0; t < 4; ++t) {
            int u = tid + t*256;             // 1024 float4 units
            int r = u >> 4, c4 = u & 15;
            int p = c4 ^ ((r >> 4) & 3);
            kt4[r*17 + p] = *(const float4*)(K + r*HWD + n0 + c4*4);
            vt4[r*17 + p] = *(const float4*)(V + r*HWD + n0 + c4*4);
        }
        __syncthreads();
        float4 s4[16];
        #pragma unroll
        for (int nb = 0; nb < 16; ++nb) { s4[nb].x=0.f; s4[nb].y=0.f; s4[nb].z=0.f; s4[nb].w=0.f; }
        #pragma unroll
        for (int k = 0; k < 16; ++k) {
            const float4* kr = &kt4[(cq*16+k)*17];
            float qk = q[k];
            #pragma unroll
            for (int nb = 0; nb < 16; ++nb) {
                float4 kv = kr[nb ^ cq];
                s4[nb].x += qk*kv.x; s4[nb].y += qk*kv.y;
                s4[nb].z += qk*kv.z; s4[nb].w += qk*kv.w;
            }
        }
        // reduce across the 4 cq lanes of each quad
        #pragma unroll
        for (int nb = 0; nb < 16; ++nb) {
            s4[nb].x += __shfl_xor(s4[nb].x, 1); s4[nb].x += __shfl_xor(s4[nb].x, 2);
            s4[nb].y += __shfl_xor(s4[nb].y, 1); s4[nb].y += __shfl_xor(s4[nb].y, 2);
            s4[nb].z += __shfl_xor(s4[nb].z, 1); s4[nb].z += __shfl_xor(s4[nb].z, 2);
            s4[nb].w += __shfl_xor(s4[nb].w, 1); s4[nb].w += __shfl_xor(s4[nb].w, 2);
        }
        float tm = -3.0e38f;
        #pragma unroll
        for (int nb = 0; nb < 16; ++nb)
            tm = fmaxf(tm, fmaxf(fmaxf(s4[nb].x, s4[nb].y), fmaxf(s4[nb].z, s4[nb].w)));
        float nmx = fmaxf(mx, tm);
        float sc = __expf(mx - nmx);
        float ts = 0.f;
        #pragma unroll
        for (int nb = 0; nb < 16; ++nb) {
            s4[nb].x = __expf(s4[nb].x - nmx); s4[nb].y = __expf(s4[nb].y - nmx);
            s4[nb].z = __expf(s4[nb].z - nmx); s4[nb].w = __expf(s4[nb].w - nmx);
            ts += s4[nb].x + s4[nb].y + s4[nb].z + s4[nb].w;
        }
        l = l * sc + ts;
        mx = nmx;
        #pragma unroll
        for (int k = 0; k < 16; ++k) {
            const float4* vr = &vt4[(cq*16+k)*17];
            float a = acc[k] * sc;
            #pragma unroll
            for (int nb = 0; nb < 16; ++nb) {
                float4 vv = vr[nb ^ cq];
                a += s4[nb].x*vv.x + s4[nb].y*vv.y + s4[nb].z*vv.z + s4[nb].w*vv.w;
            }
            acc[k] = a;
        }
    }
    float inv = 1.f / l;
    #pragma unroll
    for (int k = 0; k < 16; ++k) O[(cq*16+k)*HWD + m] = acc[k] * inv;
}

// z = zbase + blockIdx.z; z<4 -> inter j=z (out slot = blockIdx.z*16+inst),
// z==4 -> intra. Batched: grid (16,16,5), zbase=0. Fallback: grid.z=1 slices.
__global__ __launch_bounds__(256) void flash_all_kernel(
    const float* __restrict__ h, const float* __restrict__ yt,
    const float* __restrict__ ft, const float* __restrict__ ht,
    const float* __restrict__ lt, float* __restrict__ ctx,
    float* __restrict__ mji, int zbase)
{
    __shared__ __align__(16) float4 kt4[64*17];
    __shared__ __align__(16) float4 vt4[64*17];
    int z = zbase + blockIdx.z;
    int inst = blockIdx.y;
    int m0 = blockIdx.x * 64;
    if (z < 4) {
        int b = inst & 3;
        int slot = blockIdx.z * 16 + inst;
        flash_core(h + (size_t)inst*CHW, yt + (size_t)(z*BB+b)*CHW,
                   h + (size_t)(z*BB+b)*CHW, mji + (size_t)slot*CHW, m0, kt4, vt4);
    } else {
        flash_core(ft + (size_t)inst*CHW, ht + (size_t)inst*CHW,
                   lt + (size_t)inst*CHW, ctx + (size_t)inst*CHW, m0, kt4, vt4);
    }
}

// ---------------------------------------------------------------------------
// yt[img,c,n] = sum_d Wc[c,d] * h[img,d,n]    grid (16, 8 n-chunks of 128)
// ---------------------------------------------------------------------------
__global__ __launch_bounds__(256) void yt_kernel(
    const float* __restrict__ Wc, const float* __restrict__ h,
    float* __restrict__ yt)
{
    int img = blockIdx.x;
    int n0 = blockIdx.y * 128;
    __shared__ float wc[64*64];
    __shared__ float hs[64*128];
    int tid = threadIdx.x;
    for (int i = tid; i < 4096; i += 256) wc[i] = Wc[i];
    for (int i = tid; i < 64*128; i += 256) {
        int d = i >> 7, n = i & 127;
        hs[i] = h[(size_t)img*CHW + d*HWD + n0 + n];
    }
    __syncthreads();
    int n = tid & 127;
    int c0 = (tid >> 7) * 32;
    for (int c = c0; c < c0+32; ++c) {
        float a = 0.f;
        #pragma unroll 8
        for (int d = 0; d < 64; ++d) a += wc[c*64+d] * hs[d*128+n];
        yt[(size_t)img*CHW + c*HWD + n0 + n] = a;
    }
}

// ---------------------------------------------------------------------------
// Gate stats per (slot, ci): full/top/bot/left/right/corners.
// grid nslots*64, block 64.
// ---------------------------------------------------------------------------
__global__ __launch_bounds__(64) void gate_stats_kernel(
    const float* __restrict__ mji, float* __restrict__ stats)
{
    int slot = blockIdx.x >> 6;
    int ci   = blockIdx.x & 63;
    const float* p = mji + ((size_t)slot*CC + ci)*HWD;
    int l = threadIdx.x;
    float full=0, top=0, bot=0, left=0, right=0;
    #pragma unroll
    for (int k = 0; k < 16; ++k) {
        int px = l + 64*k;
        float v = p[px];
        int y = px >> 5, x = px & 31;
        full += v;
        if (y == 0)  top += v;
        if (y == 31) bot += v;
        if (x == 0)  left += v;
        if (x == 31) right += v;
    }
    #pragma unroll
    for (int msk = 1; msk < 64; msk <<= 1) {
        full  += __shfl_xor(full,  msk);
        top   += __shfl_xor(top,   msk);
        bot   += __shfl_xor(bot,   msk);
        left  += __shfl_xor(left,  msk);
        right += __shfl_xor(right, msk);
    }
    if (l == 0) {
        float* o = stats + ((size_t)slot*CC + ci)*9;
        o[0]=full; o[1]=top; o[2]=bot; o[3]=left; o[4]=right;
        o[5]=p[0]; o[6]=p[31]; o[7]=p[992]; o[8]=p[1023];
    }
}

// gji[slot,o] = sigmoid(mean conv + bias).  grid nslots, block 64.
__global__ __launch_bounds__(64) void gate_gji_kernel(
    const float* __restrict__ stats, const float* __restrict__ wg,
    const float* __restrict__ bg, float* __restrict__ gji)
{
    int slot = blockIdx.x;
    int o = threadIdx.x;
    float acc = 0.f;
    for (int ci = 0; ci < CC; ++ci) {
        const float* st = stats + ((size_t)slot*CC + ci)*9;
        float F=st[0], T=st[1], Bo=st[2], L=st[3], R=st[4];
        float TL=st[5], TR=st[6], BL=st[7], BR=st[8];
        const float* w = wg + (o*CC + ci)*9;
        acc += w[0]*(F-Bo-R+BR) + w[1]*(F-Bo) + w[2]*(F-Bo-L+BL)
             + w[3]*(F-R)       + w[4]*F      + w[5]*(F-L)
             + w[6]*(F-T-R+TR)  + w[7]*(F-T)  + w[8]*(F-T-L+TL);
    }
    float mv = acc * (1.f/1024.f) + bg[o];
    gji[slot*CC + o] = 1.f / (1.f + __expf(-mv));
}

// ---------------------------------------------------------------------------
// Batched fusion: inter-sum over j + BN fold + agg. float4, grid 1024x256.
// ---------------------------------------------------------------------------
__global__ __launch_bounds__(256) void agg_fused_kernel(
    const float* __restrict__ ctx, const float* __restrict__ h,
    const float* __restrict__ mji, const float* __restrict__ gji,
    const float* __restrict__ alpha,
    const float* __restrict__ bn_gamma, const float* __restrict__ bn_beta,
    const float* __restrict__ bn_mean, const float* __restrict__ bn_var,
    const float* __restrict__ intra_w, const float* __restrict__ inter_w,
    float* __restrict__ agg)
{
    int u = blockIdx.x * 256 + threadIdx.x;
    int idx = u * 4;
    int img = idx >> 16;
    int c = (idx >> 10) & 63;
    int i = img >> 2;
    float4 s = {0,0,0,0};
    #pragma unroll
    for (int j = 0; j < 4; ++j) {
        float g = (j != i) ? gji[(j*16+img)*CC + c] : 0.f;
        float4 mv = *(const float4*)(mji + (size_t)(j*16+img)*CHW + (idx & 65535));
        s.x += g*mv.x; s.y += g*mv.y; s.z += g*mv.z; s.w += g*mv.w;
    }
    float scale = bn_gamma[c] / sqrtf(bn_var[c] + 1e-5f);
    float cst = 3.f * (bn_beta[c] - bn_mean[c]*scale);
    float4 cv = *(const float4*)(ctx + idx);
    float4 hv = *(const float4*)(h + idx);
    float al = alpha[0], iw = intra_w[0], ew = inter_w[0];
    float4 o;
    o.x = iw*(al*cv.x + hv.x) + ew*(scale*s.x + cst);
    o.y = iw*(al*cv.y + hv.y) + ew*(scale*s.y + cst);
    o.z = iw*(al*cv.z + hv.z) + ew*(scale*s.z + cst);
    o.w = iw*(al*cv.w + hv.w) + ew*(scale*s.w + cst);
    *(float4*)(agg + idx) = o;
}

// ---- fallback (small-ws) versions -----------------------------------------
__global__ __launch_bounds__(256) void inter_accum_kernel(
    const float* __restrict__ mji, const float* __restrict__ gji,
    float* __restrict__ acc, int j, int init)
{
    int idx = blockIdx.x * 256 + threadIdx.x;
    int iimg = idx >> 16;
    int c = (idx >> 10) & 63;
    int i = iimg >> 2;
    float v = (j != i) ? gji[iimg*CC + c] * mji[idx] : 0.f;
    if (init) acc[idx] = v; else acc[idx] += v;
}

__global__ __launch_bounds__(256) void agg_kernel(
    const float* __restrict__ ctx, const float* __restrict__ h,
    const float* __restrict__ acc, const float* __restrict__ alpha,
    const float* __restrict__ bn_gamma, const float* __restrict__ bn_beta,
    const float* __restrict__ bn_mean, const float* __restrict__ bn_var,
    const float* __restrict__ intra_w, const float* __restrict__ inter_w,
    float* __restrict__ agg)
{
    int idx = blockIdx.x * 256 + threadIdx.x;
    int c = (idx >> 10) & 63;
    float scale = bn_gamma[c] / sqrtf(bn_var[c] + 1e-5f);
    float cst = 3.f * (bn_beta[c] - bn_mean[c]*scale);
    float intra = alpha[0]*ctx[idx] + h[idx];
    float inter = scale*acc[idx] + cst;
    agg[idx] = intra_w[0]*intra + inter_w[0]*inter;
}

// ---------------------------------------------------------------------------
// 5x5 conv, 128 in-ch (agg | h), 128 out-ch, sigmoid -> zr. grid (16,128).
// Tile 36x36, halo zeroed once, interior restaged per-ci (float2 stores),
// reads are two aligned float4s per row.
// ---------------------------------------------------------------------------
__global__ __launch_bounds__(256) void conv5_zr_kernel(
    const float* __restrict__ agg, const float* __restrict__ h,
    const float* __restrict__ w, const float* __restrict__ bias,
    float* __restrict__ zr)
{
    int img = blockIdx.x;
    int co  = blockIdx.y;
    __shared__ __align__(16) float tile[36*36];
    int tid = threadIdx.x;
    float acc[4] = {0,0,0,0};
    int px0 = tid * 4;
    int oy = px0 >> 5, ox = px0 & 31;
    int sr = tid >> 3;
    int sc = (tid & 7) * 4;
    for (int idx = tid; idx < 36*36; idx += 256) tile[idx] = 0.f;
    for (int ci = 0; ci < 128; ++ci) {
        const float* src = (ci < 64) ? (agg + (size_t)img*CHW + ci*HWD)
                                     : (h + (size_t)img*CHW + (ci-64)*HWD);
        __syncthreads();
        {
            float4 v = *(const float4*)(src + sr*32 + sc);
            float* dst = &tile[(sr+2)*36 + 2 + sc];
            float2 lo = {v.x, v.y}, hi = {v.z, v.w};
            *(float2*)dst = lo;
            *(float2*)(dst+2) = hi;
        }
        __syncthreads();
        const float* pw = w + (co*128 + ci)*25;
        float wv[25];
        #pragma unroll
        for (int k = 0; k < 25; ++k) wv[k] = pw[k];
        #pragma unroll
        for (int dy = 0; dy < 5; ++dy) {
            const float* trow = &tile[(oy+dy)*36 + ox];
            float4 a4 = *(const float4*)trow;
            float4 b4 = *(const float4*)(trow + 4);
            float in[8] = {a4.x,a4.y,a4.z,a4.w,b4.x,b4.y,b4.z,b4.w};
            #pragma unroll
            for (int dx = 0; dx < 5; ++dx) {
                float wk = wv[dy*5+dx];
                #pragma unroll
                for (int p = 0; p < 4; ++p) acc[p] += wk * in[dx+p];
            }
        }
    }
    float bv = bias[co];
    size_t out = (size_t)img*128*HWD + co*HWD + px0;
    float4 o;
    o.x = 1.f/(1.f+__expf(-(acc[0]+bv)));
    o.y = 1.f/(1.f+__expf(-(acc[1]+bv)));
    o.z = 1.f/(1.f+__expf(-(acc[2]+bv)));
    o.w = 1.f/(1.f+__expf(-(acc[3]+bv)));
    *(float4*)(zr + out) = o;
}

// 5x5 conv, 128 in-ch (agg | r*h), 64 out-ch, tanh -> h_hat. grid (16,64)
__global__ __launch_bounds__(256) void conv5_hh_kernel(
    const float* __restrict__ agg, const float* __restrict__ h,
    const float* __restrict__ zr, const float* __restrict__ w,
    const float* __restrict__ bias, float* __restrict__ hh)
{
    int img = blockIdx.x;
    int co  = blockIdx.y;
    __shared__ __align__(16) float tile[36*36];
    int tid = threadIdx.x;
    float acc[4] = {0,0,0,0};
    int px0 = tid * 4;
    int oy = px0 >> 5, ox = px0 & 31;
    int sr = tid >> 3;
    int sc = (tid & 7) * 4;
    for (int idx = tid; idx < 36*36; idx += 256) tile[idx] = 0.f;
    for (int ci = 0; ci < 128; ++ci) {
        __syncthreads();
        {
            float4 v;
            if (ci < 64) {
                v = *(const float4*)(agg + (size_t)img*CHW + ci*HWD + sr*32 + sc);
            } else {
                float4 a = *(const float4*)(h + (size_t)img*CHW + (ci-64)*HWD + sr*32 + sc);
                float4 b = *(const float4*)(zr + (size_t)img*128*HWD + ci*HWD + sr*32 + sc);
                v.x = a.x*b.x; v.y = a.y*b.y; v.z = a.z*b.z; v.w = a.w*b.w;
            }
            float* dst = &tile[(sr+2)*36 + 2 + sc];
            float2 lo = {v.x, v.y}, hi = {v.z, v.w};
            *(float2*)dst = lo;
            *(float2*)(dst+2) = hi;
        }
        __syncthreads();
        const float* pw = w + (co*128 + ci)*25;
        float wv[25];
        #pragma unroll
        for (int k = 0; k < 25; ++k) wv[k] = pw[k];
        #pragma unroll
        for (int dy = 0; dy < 5; ++dy) {
            const float* trow = &tile[(oy+dy)*36 + ox];
            float4 a4 = *(const float4*)trow;
            float4 b4 = *(const float4*)(trow + 4);
            float in[8] = {a4.x,a4.y,a4.z,a4.w,b4.x,b4.y,b4.z,b4.w};
            #pragma unroll
            for (int dx = 0; dx < 5; ++dx) {
                float wk = wv[dy*5+dx];
                #pragma unroll
                for (int p = 0; p < 4; ++p) acc[p] += wk * in[dx+p];
            }
        }
    }
    float bv = bias[co];
    size_t out = (size_t)img*CHW + co*HWD + px0;
    float4 o;
    o.x = tanhf(acc[0]+bv); o.y = tanhf(acc[1]+bv);
    o.z = tanhf(acc[2]+bv); o.w = tanhf(acc[3]+bv);
    *(float4*)(hh + out) = o;
}

// h = (2-z)*h + z*h_hat   (float4, grid 1024)
__global__ __launch_bounds__(256) void gru_update_kernel(
    const float* __restrict__ zr, const float* __restrict__ hh,
    float* __restrict__ h)
{
    int idx = (blockIdx.x * 256 + threadIdx.x) * 4;
    int img = idx >> 16;
    int rem = idx & 65535;
    float4 z = *(const float4*)(zr + (size_t)img*131072 + rem);
    float4 hv = *(const float4*)(h + idx);
    float4 hhv = *(const float4*)(hh + idx);
    float4 o;
    o.x = (2.f-z.x)*hv.x + z.x*hhv.x;
    o.y = (2.f-z.y)*hv.y + z.y*hhv.y;
    o.z = (2.f-z.z)*hv.z + z.z*hhv.z;
    o.w = (2.f-z.w)*hv.w + z.w*hhv.w;
    *(float4*)(h + idx) = o;
}

// ---------------------------------------------------------------------------
extern "C" void kernel_launch(void* const* d_in, const int* in_sizes, int n_in,
                              void* d_out, int out_size, void* d_ws, size_t ws_size,
                              hipStream_t stream)
{
    const float* x        = (const float*)d_in[0];
    const float* Wf_w     = (const float*)d_in[1];
    const float* Wf_b     = (const float*)d_in[2];
    const float* Wh_w     = (const float*)d_in[3];
    const float* Wh_b     = (const float*)d_in[4];
    const float* Wl_w     = (const float*)d_in[5];
    const float* Wl_b     = (const float*)d_in[6];
    const float* alpha    = (const float*)d_in[7];
    const float* Wc       = (const float*)d_in[8];
    const float* Wg_w     = (const float*)d_in[9];
    const float* Wg_b     = (const float*)d_in[10];
    const float* bn_gamma = (const float*)d_in[11];
    const float* bn_beta  = (const float*)d_in[12];
    const float* bn_mean  = (const float*)d_in[13];
    const float* bn_var   = (const float*)d_in[14];
    const float* gru_zr_w = (const float*)d_in[15];
    const float* gru_zr_b = (const float*)d_in[16];
    const float* gru_h_w  = (const float*)d_in[17];
    const float* gru_h_b  = (const float*)d_in[18];
    const float* intra_w  = (const float*)d_in[19];
    const float* inter_w  = (const float*)d_in[20];

    float* h  = (float*)d_out;
    float* ws = (float*)d_ws;
    const size_t M = 1048576;

    hipMemcpyAsync(h, x, M * sizeof(float), hipMemcpyDeviceToDevice, stream);

    // batched needs: 9M floats + stats(64*64*9) + gji(64*64)
    const size_t NEED_BATCHED = (9*M + 64*64*9 + 64*64) * sizeof(float);
    bool batched = (ws_size >= NEED_BATCHED);

    if (batched) {
        float* ft    = ws;          // reused as agg
        float* ht_   = ws + 1*M;    // reused as zr (with lt)
        float* lt    = ws + 2*M;
        float* ctx   = ws + 3*M;
        float* yt    = ws + 4*M;    // reused as h_hat
        float* mji   = ws + 5*M;    // 4 slots x 1M
        float* stats = ws + 9*M;
        float* gji   = stats + 64*64*9;
        float* agg   = ft;
        float* zr    = ht_;
        float* hh    = yt;

        for (int it = 0; it < 3; ++it) {
            conv3_triple_kernel<<<dim3(NIMG, CC), 256, 0, stream>>>(
                h, Wf_w, Wf_b, Wh_w, Wh_b, Wl_w, Wl_b, ft, ht_, lt);
            yt_kernel<<<dim3(NIMG, 8), 256, 0, stream>>>(Wc, h, yt);
            flash_all_kernel<<<dim3(16, NIMG, 5), 256, 0, stream>>>(
                h, yt, ft, ht_, lt, ctx, mji, 0);
            gate_stats_kernel<<<64*64, 64, 0, stream>>>(mji, stats);
            gate_gji_kernel<<<64, 64, 0, stream>>>(stats, Wg_w, Wg_b, gji);
            agg_fused_kernel<<<1024, 256, 0, stream>>>(ctx, h, mji, gji, alpha,
                bn_gamma, bn_beta, bn_mean, bn_var, intra_w, inter_w, agg);
            conv5_zr_kernel<<<dim3(NIMG, 128), 256, 0, stream>>>(agg, h, gru_zr_w, gru_zr_b, zr);
            conv5_hh_kernel<<<dim3(NIMG, 64), 256, 0, stream>>>(agg, h, zr, gru_h_w, gru_h_b, hh);
            gru_update_kernel<<<1024, 256, 0, stream>>>(zr, hh, h);
        }
    } else {
        float* ft    = ws;
        float* ht_   = ws + 1*M;
        float* lt    = ws + 2*M;
        float* ctx   = ws + 3*M;
        float* yt    = ws + 4*M;
        float* mji   = ws + 5*M;    // single slot
        float* iacc  = ws + 6*M;
        float* stats = ws + 7*M;
        float* gji   = stats + 16*64*9;
        float* agg   = ft;
        float* zr    = ht_;
        float* hh    = yt;

        for (int it = 0; it < 3; ++it) {
            conv3_triple_kernel<<<dim3(NIMG, CC), 256, 0, stream>>>(
                h, Wf_w, Wf_b, Wh_w, Wh_b, Wl_w, Wl_b, ft, ht_, lt);
            yt_kernel<<<dim3(NIMG, 8), 256, 0, stream>>>(Wc, h, yt);
            flash_all_kernel<<<dim3(16, NIMG, 1), 256, 0, stream>>>(
                h, yt, ft, ht_, lt, ctx, mji, 4);   // intra
            for (int j = 0; j < SS; ++j) {
                flash_all_kernel<<<dim3(16, NIMG, 1), 256, 0, stream>>>(
                    h, yt, ft, ht_, lt, ctx, mji, j);
                gate_stats_kernel<<<16*64, 64, 0, stream>>>(mji, stats);
                gate_gji_kernel<<<16, 64, 0, stream>>>(stats, Wg_w, Wg_b, gji);
                inter_accum_kernel<<<4096, 256, 0, stream>>>(mji, gji, iacc, j, j == 0 ? 1 : 0);
            }
            agg_kernel<<<4096, 256, 0, stream>>>(ctx, h, iacc, alpha,
                bn_gamma, bn_beta, bn_mean, bn_var, intra_w, inter_w, agg);
            conv5_zr_kernel<<<dim3(NIMG, 128), 256, 0, stream>>>(agg, h, gru_zr_w, gru_zr_b, zr);
            conv5_hh_kernel<<<dim3(NIMG, 64), 256, 0, stream>>>(agg, h, zr, gru_h_w, gru_h_b, hh);
            gru_update_kernel<<<1024, 256, 0, stream>>>(zr, hh, h);
        }
    }
}